// Round 1
// baseline (178.899 us; speedup 1.0000x reference)
//
#include <hip/hip_runtime.h>
#include <cstdint>
#include <cstddef>

// ---------- types ----------
typedef __bf16 bf16;
typedef __bf16 bf16x8 __attribute__((ext_vector_type(8)));
typedef __bf16 bf16x2 __attribute__((ext_vector_type(2)));
typedef float  floatx4 __attribute__((ext_vector_type(4)));

typedef __attribute__((address_space(1))) void gvoid_t;
typedef __attribute__((address_space(3))) void lvoid_t;

#define MFMA16(a, b, c) __builtin_amdgcn_mfma_f32_16x16x32_bf16((a), (b), (c), 0, 0, 0)

#if __has_builtin(__builtin_amdgcn_exp2f)
#define EXP2(x) __builtin_amdgcn_exp2f(x)
#else
#define EXP2(x) exp2f(x)
#endif

// B=2, S=2048, D=1024, H=16, DH=64; tokens NT=4096; E3=3072
#define S_TOK 2048
#define E3 3072
#define DMODEL 1024

// ---------- fused fp32 -> bf16 convert (X, Wqkv w/ Q-scale, Wout) ----------
#define NX 4194304
#define NWQ 3145728
#define NWO 1048576
__global__ __launch_bounds__(256) void cvt_all(const float* __restrict__ X,
                                               const float* __restrict__ Wq,
                                               const float* __restrict__ Wo,
                                               bf16* __restrict__ Xb,
                                               bf16* __restrict__ Wqb,
                                               bf16* __restrict__ Wob) {
  int i = (blockIdx.x * 256 + threadIdx.x) * 8;
  const float* s;
  bf16* d;
  float sc = 1.0f;
  int off;
  if (i < NX) {
    s = X; d = Xb; off = i;
  } else if (i < NX + NWQ) {
    off = i - NX; s = Wq; d = Wqb;
    int row = off >> 10;  // D=1024 per row; rows with e%192<64 produce Q
    if ((row % 192) < 64) sc = 0.18033688011f;  // 0.125*log2(e) pre-folded
  } else {
    off = i - NX - NWQ; s = Wo; d = Wob;
  }
  const float4* p = (const float4*)(s + off);
  float4 a = p[0], b = p[1];
  bf16x8 o;
  o[0] = (bf16)(a.x * sc); o[1] = (bf16)(a.y * sc);
  o[2] = (bf16)(a.z * sc); o[3] = (bf16)(a.w * sc);
  o[4] = (bf16)(b.x * sc); o[5] = (bf16)(b.y * sc);
  o[6] = (bf16)(b.z * sc); o[7] = (bf16)(b.w * sc);
  *(bf16x8*)(d + off) = o;
}

// ---------- async global->LDS, 16B per lane ----------
__device__ __forceinline__ void gl_lds16(const bf16* g, bf16* l) {
  __builtin_amdgcn_global_load_lds((gvoid_t*)g, (lvoid_t*)l, 16, 0, 0);
}

// ---------- GEMM: BK=64, XOR-swizzled LDS; optional fused V-transpose ----------
template <bool OUT_BF16, bool FUSE_V>
__global__ __launch_bounds__(256) void gemm_bt(const bf16* __restrict__ A,
                                               const bf16* __restrict__ Bt,
                                               void* __restrict__ Cv,
                                               bf16* __restrict__ Vt,
                                               int M, int N, int K) {
  __shared__ bf16 sA[128 * 64];  // 16 KB
  __shared__ bf16 sB[128 * 64];  // 16 KB
  const int tid = threadIdx.x;
  const int wv = tid >> 6, lane = tid & 63;
  const int wr = wv >> 1, wc = wv & 1;
  const int lrow = lane & 15, lgrp = lane >> 4;
  const int R0 = blockIdx.y * 128, C0 = blockIdx.x * 128;

  floatx4 acc[4][4] = {};

  const int srow = lane >> 3;
  const int schk = (lane & 7) ^ srow;  // source chunk, swizzle key = row&7
  const bf16* gA = A + (size_t)(R0 + wv * 32 + srow) * K + schk * 8;
  const bf16* gB = Bt + (size_t)(C0 + wv * 32 + srow) * K + schk * 8;
  bf16* lA = sA + wv * 32 * 64;
  bf16* lB = sB + wv * 32 * 64;
  const size_t rs8 = (size_t)8 * K;

  for (int k0 = 0; k0 < K; k0 += 64) {
#pragma unroll
    for (int c = 0; c < 4; c++) {
      gl_lds16(gA + k0 + c * rs8, lA + c * 512);
      gl_lds16(gB + k0 + c * rs8, lB + c * 512);
    }
    __syncthreads();
#pragma unroll
    for (int kk = 0; kk < 2; kk++) {
      bf16x8 af[4], bfr[4];
#pragma unroll
      for (int i = 0; i < 4; i++) {
        int r = wr * 64 + i * 16 + lrow;
        af[i] = *(const bf16x8*)&sA[r * 64 + ((kk * 4 + lgrp) ^ (r & 7)) * 8];
      }
#pragma unroll
      for (int j = 0; j < 4; j++) {
        int r = wc * 64 + j * 16 + lrow;
        bfr[j] = *(const bf16x8*)&sB[r * 64 + ((kk * 4 + lgrp) ^ (r & 7)) * 8];
      }
#pragma unroll
      for (int i = 0; i < 4; i++)
#pragma unroll
        for (int j = 0; j < 4; j++)
          acc[i][j] = MFMA16(af[i], bfr[j], acc[i][j]);
    }
    __syncthreads();
  }

  const int rbase = R0 + wr * 64 + lgrp * 4;
  const int cbase = C0 + wc * 64 + lrow;
  if (OUT_BF16) {
    bf16* C = (bf16*)Cv;
#pragma unroll
    for (int i = 0; i < 4; i++)
#pragma unroll
      for (int j = 0; j < 4; j++) {
        const int col = cbase + j * 16;
        const int m192 = col % 192;
        const int hh = col / 192;
#pragma unroll
        for (int r = 0; r < 4; r++) {
          const int row = rbase + i * 16 + r;
          bf16 val = (bf16)acc[i][j][r];
          bf16* dst;
          if (FUSE_V && m192 >= 128) {
            const int sl = row & 2047;
            const int sp = (sl & ~31) | ((sl & 15) << 1) | ((sl >> 4) & 1);
            dst = Vt + ((size_t)(((row >> 11) * 16 + hh) * 64 + (m192 - 128))) * S_TOK + sp;
          } else {
            dst = C + (size_t)row * N + col;
          }
          *dst = val;
        }
      }
  } else {
    float* C = (float*)Cv;
#pragma unroll
    for (int i = 0; i < 4; i++)
#pragma unroll
      for (int j = 0; j < 4; j++)
#pragma unroll
        for (int r = 0; r < 4; r++)
          C[(size_t)(rbase + i * 16 + r) * N + cbase + j * 16] = acc[i][j][r];
  }
}

// ---------- GEMM 128x64 tile (out-proj: N=1024 -> 512 blocks, 2/CU) ----------
__global__ __launch_bounds__(256) void gemm_bt_n64(const bf16* __restrict__ A,
                                                   const bf16* __restrict__ Bt,
                                                   float* __restrict__ C,
                                                   int M, int N, int K) {
  __shared__ bf16 sA[128 * 64];  // 16 KB
  __shared__ bf16 sB[64 * 64];   //  8 KB
  const int tid = threadIdx.x;
  const int wv = tid >> 6, lane = tid & 63;
  const int wr = wv >> 1, wc = wv & 1;
  const int lrow = lane & 15, lgrp = lane >> 4;
  const int R0 = blockIdx.y * 128, C0 = blockIdx.x * 64;

  floatx4 acc[4][2] = {};

  const int srow = lane >> 3;
  const int schk = (lane & 7) ^ srow;
  const bf16* gA = A + (size_t)(R0 + wv * 32 + srow) * K + schk * 8;
  const bf16* gB = Bt + (size_t)(C0 + wv * 16 + srow) * K + schk * 8;
  bf16* lA = sA + wv * 32 * 64;
  bf16* lB = sB + wv * 16 * 64;
  const size_t rs8 = (size_t)8 * K;

  for (int k0 = 0; k0 < K; k0 += 64) {
#pragma unroll
    for (int c = 0; c < 4; c++) gl_lds16(gA + k0 + c * rs8, lA + c * 512);
#pragma unroll
    for (int c = 0; c < 2; c++) gl_lds16(gB + k0 + c * rs8, lB + c * 512);
    __syncthreads();
#pragma unroll
    for (int kk = 0; kk < 2; kk++) {
      bf16x8 af[4], bfr[2];
#pragma unroll
      for (int i = 0; i < 4; i++) {
        int r = wr * 64 + i * 16 + lrow;
        af[i] = *(const bf16x8*)&sA[r * 64 + ((kk * 4 + lgrp) ^ (r & 7)) * 8];
      }
#pragma unroll
      for (int j = 0; j < 2; j++) {
        int r = wc * 32 + j * 16 + lrow;
        bfr[j] = *(const bf16x8*)&sB[r * 64 + ((kk * 4 + lgrp) ^ (r & 7)) * 8];
      }
#pragma unroll
      for (int i = 0; i < 4; i++)
#pragma unroll
        for (int j = 0; j < 2; j++)
          acc[i][j] = MFMA16(af[i], bfr[j], acc[i][j]);
    }
    __syncthreads();
  }

  const int rbase = R0 + wr * 64 + lgrp * 4;
  const int cbase = C0 + wc * 32 + lrow;
#pragma unroll
  for (int i = 0; i < 4; i++)
#pragma unroll
    for (int j = 0; j < 2; j++)
#pragma unroll
      for (int r = 0; r < 4; r++)
        C[(size_t)(rbase + i * 16 + r) * N + cbase + j * 16] = acc[i][j][r];
}

// ---------- attention v11: XCD-resident K/V + cross-group sP pipeline ----------
// v10 postmortem: MfmaUtil 25 / VALU 22 / Occ 18 -> latency-bound at 2 waves/SIMD.
// Stall 1: grid (qb,h,b) put same-(b,h) q-blocks on 8 different XCDs -> K/V
//   working set 16MB/XCD vs 4MB L2 -> FETCH 69.7MB (~3x ideal), HBM-class
//   staging latency. Fix: grid (h,qb,b) -> XCD k hosts 4 (b,h) pairs = 2MB
//   K/V, L2-resident.
// Stall 2: per-group sP write->read turnaround (~240cy) exposed 4x/stage.
//   Fix: double-buffer sP by group parity; order qk(g+1) before pv(g) so the
//   turnaround is covered by kf loads + 8 QK MFMAs. setprio(1) around MFMA
//   clusters (T5: applies, waves here are phase-independent).
__global__ __launch_bounds__(512, 2) void attn(const bf16* __restrict__ qkv,
                                               const bf16* __restrict__ Vt,
                                               bf16* __restrict__ vals) {
  __shared__ bf16 sK[2][128 * 64];   // 32 KB [buf][key][dh]
  __shared__ bf16 sV[2][64 * 128];   // 32 KB [buf][d][key']
  __shared__ bf16 sP[8][2][2][640];  // 40 KB [wave][rowtile][gbuf] P round-trip

  const int tid = threadIdx.x;
  const int wv = tid >> 6, lane = tid & 63;
  const int lrow = lane & 15, lgrp = lane >> 4;
  const int b = blockIdx.z, h = blockIdx.x;   // x=h: same-(b,h) blocks share XCD
  const int qb = blockIdx.y * 256;

  // K staging: wave w covers key-rows [w*8,w*8+8) and [64+w*8, ...+8)
  const int srow = lane >> 3;          // 0..7
  const int scol = (lane & 7) ^ srow;  // 8-chunk swizzle, key = row&7 = srow
  const bf16* kg0 = qkv + (size_t)(b * S_TOK + wv * 8 + srow) * E3 + h * 192 + 64 + scol * 8;
  // V staging: wave w covers d-rows [w*8,w*8+8) as 2 calls of 4 rows
  const int vrow = lane >> 4;          // 0..3
  const int vchk = lane & 15;          // dest chunk (16-chunk rows)
  const int d0 = wv * 8 + vrow, d1 = d0 + 4;
  const bf16* vg0 = Vt + (size_t)((b * 16 + h) * 64 + d0) * S_TOK + (vchk ^ (d0 & 15)) * 8;
  const bf16* vg1 = Vt + (size_t)((b * 16 + h) * 64 + d1) * S_TOK + (vchk ^ (d1 & 15)) * 8;

  // Q A-fragments for two row-tiles (pre-scaled): A[m=lane&15][k=lgrp*8+j]
  const bf16* qp = qkv + (size_t)(b * S_TOK + qb + wv * 32) * E3 + h * 192;
  bf16x8 qa[2][2];
#pragma unroll
  for (int rt = 0; rt < 2; rt++)
#pragma unroll
    for (int dh = 0; dh < 2; dh++)
      qa[rt][dh] = *(const bf16x8*)(qp + (size_t)(rt * 16 + lrow) * E3 + dh * 32 + lgrp * 8);

  floatx4 O[2][4] = {};
  floatx4 lacc[2] = {};
  floatx4 sc[2][2];  // [rowtile][keytile] score regs held across the pipeline
  bf16x8 ones;
  const bf16 one1 = (bf16)1.0f;
#pragma unroll
  for (int j = 0; j < 8; j++) ones[j] = one1;

  auto stage = [&](int buf, int st) {
    const bf16* kg = kg0 + (size_t)st * 128 * E3;
    gl_lds16(kg, &sK[buf][wv * 512]);
    gl_lds16(kg + (size_t)64 * E3, &sK[buf][4096 + wv * 512]);
    gl_lds16(vg0 + st * 128, &sV[buf][wv * 1024]);
    gl_lds16(vg1 + st * 128, &sV[buf][wv * 1024 + 512]);
  };

  // QK^T MFMAs for 32-key group g -> sc regs
  auto qk_g = [&](int buf, int g) {
    bf16x8 kf[2][2];
#pragma unroll
    for (int t = 0; t < 2; t++)
#pragma unroll
      for (int dh = 0; dh < 2; dh++)
        kf[t][dh] = *(const bf16x8*)&sK[buf][(g * 32 + t * 16 + lrow) * 64 +
                                            ((dh * 4 + lgrp) ^ (lrow & 7)) * 8];
    __builtin_amdgcn_s_setprio(1);
#pragma unroll
    for (int rt = 0; rt < 2; rt++) {
      floatx4 a0 = {0.f, 0.f, 0.f, 0.f}, a1 = {0.f, 0.f, 0.f, 0.f};
      a0 = MFMA16(qa[rt][0], kf[0][0], a0);
      a0 = MFMA16(qa[rt][1], kf[0][1], a0);
      a1 = MFMA16(qa[rt][0], kf[1][0], a1);
      a1 = MFMA16(qa[rt][1], kf[1][1], a1);
      sc[rt][0] = a0;
      sc[rt][1] = a1;
    }
    __builtin_amdgcn_s_setprio(0);
  };

  // exp2 + pack -> sP[gbuf g&1]
  auto expw_g = [&](int g) {
#pragma unroll
    for (int rt = 0; rt < 2; rt++)
#pragma unroll
      for (int r = 0; r < 4; r++) {
        bf16x2 h2;
        h2[0] = (bf16)EXP2(sc[rt][0][r]);
        h2[1] = (bf16)EXP2(sc[rt][1][r]);
        *(unsigned*)&sP[wv][rt][g & 1][(lgrp * 4 + r) * 40 + lrow * 2] =
            __builtin_bit_cast(unsigned, h2);
      }
  };

  // PV MFMAs for group g (reads sP[gbuf g&1], written one group earlier)
  auto pv_g = [&](int buf, int g) {
    bf16x8 vf[4];
#pragma unroll
    for (int dt = 0; dt < 4; dt++)
      vf[dt] = *(const bf16x8*)&sV[buf][(dt * 16 + lrow) * 128 + ((g * 4 + lgrp) ^ lrow) * 8];
    __builtin_amdgcn_s_setprio(1);
#pragma unroll
    for (int rt = 0; rt < 2; rt++) {
      bf16x8 pf = *(const bf16x8*)&sP[wv][rt][g & 1][lrow * 40 + lgrp * 8];
#pragma unroll
      for (int dt = 0; dt < 4; dt++) O[rt][dt] = MFMA16(pf, vf[dt], O[rt][dt]);
      lacc[rt] = MFMA16(pf, ones, lacc[rt]);
    }
    __builtin_amdgcn_s_setprio(0);
  };

  // order: write(g)->read(g) gap is filled by qk(g+1)+expw(g+1) (~250cy);
  // sP gbuf parity alternates so no WAR hazard within the sequence.
  auto compute = [&](int buf) {
    qk_g(buf, 0); expw_g(0);
    qk_g(buf, 1); expw_g(1);
    pv_g(buf, 0);
    qk_g(buf, 2); expw_g(2);
    pv_g(buf, 1);
    qk_g(buf, 3); expw_g(3);
    pv_g(buf, 2);
    pv_g(buf, 3);
  };

  stage(0, 0);
  __syncthreads();
#pragma unroll 1
  for (int st = 0; st < 16; st += 2) {
    stage(1, st + 1);
    compute(0);
    __syncthreads();
    if (st + 2 < 16) stage(0, st + 2);
    compute(1);
    __syncthreads();
  }

  bf16* vout = vals + (size_t)(b * S_TOK + qb + wv * 32) * DMODEL + h * 64;
#pragma unroll
  for (int rt = 0; rt < 2; rt++)
#pragma unroll
    for (int r = 0; r < 4; r++) {
      float rinv = __builtin_amdgcn_rcpf(lacc[rt][r]);
#pragma unroll
      for (int dt = 0; dt < 4; dt++)
        vout[(size_t)(rt * 16 + lgrp * 4 + r) * DMODEL + dt * 16 + lrow] =
            (bf16)(O[rt][dt][r] * rinv);
    }
}

// ---------- host ----------
extern "C" void kernel_launch(void* const* d_in, const int* in_sizes, int n_in,
                              void* d_out, int out_size, void* d_ws, size_t ws_size,
                              hipStream_t stream) {
  const float* X = (const float*)d_in[0];     // (2,2048,1024)
  const float* Wqkv = (const float*)d_in[1];  // (3072,1024)
  const float* Wout = (const float*)d_in[2];  // (1024,1024)
  float* out = (float*)d_out;                 // (2,2048,1024)

  char* ws = (char*)d_ws;
  bf16* Xb = (bf16*)(ws);                          //  8 MB
  bf16* Wqb = (bf16*)(ws + ((size_t)8 << 20));     //  6 MB
  bf16* Wob = (bf16*)(ws + ((size_t)14 << 20));    //  2 MB
  bf16* qkvb = (bf16*)(ws + ((size_t)16 << 20));   // 24 MB (4096 x 3072; V-part unused)
  bf16* Vt = (bf16*)(ws + ((size_t)40 << 20));     //  8 MB (2*16*64 x 2048)
  bf16* vals = (bf16*)(ws + ((size_t)48 << 20));   //  8 MB (4096 x 1024)

  cvt_all<<<(NX + NWQ + NWO) / 2048, 256, 0, stream>>>(X, Wqkv, Wout, Xb, Wqb, Wob);

  // qkv = X @ Wqkv^T, V-part written straight to Vt (sigma-permuted)
  gemm_bt<true, true><<<dim3(24, 32), 256, 0, stream>>>(Xb, Wqb, qkvb, Vt, 4096, 3072, 1024);

  // grid (h, qb, b): linear%8 = h%8 -> each XCD owns 4 (b,h) pairs' K/V (2MB, L2-fit)
  attn<<<dim3(16, 8, 2), 512, 0, stream>>>(qkvb, Vt, vals);

  // out = vals @ Wout^T : 128x64 tiles -> 512 blocks (2/CU)
  gemm_bt_n64<<<dim3(16, 32), 256, 0, stream>>>(vals, Wob, out, 4096, 1024, 1024);
}

// Round 2
// 171.588 us; speedup vs baseline: 1.0426x; 1.0426x over previous
//
#include <hip/hip_runtime.h>
#include <cstdint>
#include <cstddef>

// ---------- types ----------
typedef __bf16 bf16;
typedef __bf16 bf16x8 __attribute__((ext_vector_type(8)));
typedef __bf16 bf16x2 __attribute__((ext_vector_type(2)));
typedef float  floatx4 __attribute__((ext_vector_type(4)));
typedef unsigned uintx4 __attribute__((ext_vector_type(4)));

typedef __attribute__((address_space(1))) void gvoid_t;
typedef __attribute__((address_space(3))) void lvoid_t;

#define MFMA16(a, b, c) __builtin_amdgcn_mfma_f32_16x16x32_bf16((a), (b), (c), 0, 0, 0)

#if __has_builtin(__builtin_amdgcn_exp2f)
#define EXP2(x) __builtin_amdgcn_exp2f(x)
#else
#define EXP2(x) exp2f(x)
#endif

// B=2, S=2048, D=1024, H=16, DH=64; tokens NT=4096; E3=3072
#define S_TOK 2048
#define E3 3072
#define DMODEL 1024

// ---------- fused fp32 -> bf16 convert (X, Wqkv w/ Q-scale, Wout) ----------
#define NX 4194304
#define NWQ 3145728
#define NWO 1048576
__global__ __launch_bounds__(256) void cvt_all(const float* __restrict__ X,
                                               const float* __restrict__ Wq,
                                               const float* __restrict__ Wo,
                                               bf16* __restrict__ Xb,
                                               bf16* __restrict__ Wqb,
                                               bf16* __restrict__ Wob) {
  int i = (blockIdx.x * 256 + threadIdx.x) * 8;
  const float* s;
  bf16* d;
  float sc = 1.0f;
  int off;
  if (i < NX) {
    s = X; d = Xb; off = i;
  } else if (i < NX + NWQ) {
    off = i - NX; s = Wq; d = Wqb;
    int row = off >> 10;  // D=1024 per row; rows with e%192<64 produce Q
    if ((row % 192) < 64) sc = 0.18033688011f;  // 0.125*log2(e) pre-folded
  } else {
    off = i - NX - NWQ; s = Wo; d = Wob;
  }
  const float4* p = (const float4*)(s + off);
  float4 a = p[0], b = p[1];
  bf16x8 o;
  o[0] = (bf16)(a.x * sc); o[1] = (bf16)(a.y * sc);
  o[2] = (bf16)(a.z * sc); o[3] = (bf16)(a.w * sc);
  o[4] = (bf16)(b.x * sc); o[5] = (bf16)(b.y * sc);
  o[6] = (bf16)(b.z * sc); o[7] = (bf16)(b.w * sc);
  *(bf16x8*)(d + off) = o;
}

// ---------- async global->LDS, 16B per lane ----------
__device__ __forceinline__ void gl_lds16(const bf16* g, bf16* l) {
  __builtin_amdgcn_global_load_lds((gvoid_t*)g, (lvoid_t*)l, 16, 0, 0);
}

// ---------- GEMM: BK=64, XOR-swizzled LDS; optional fused V-transpose ----------
// FUSE_V key-slot permutation (within each 32-token group), co-designed with
// attn's in-register P exchange: slot k=hi*8+r holds key hi*4+r (t0 chunk,
// lane-own) and slot k=hi*8+4+r holds key 16+(hi^2)*4+r (t1 chunk, pulled
// from lane^32 via ds_bpermute). Bijective on [0,32).
template <bool OUT_BF16, bool FUSE_V>
__global__ __launch_bounds__(256) void gemm_bt(const bf16* __restrict__ A,
                                               const bf16* __restrict__ Bt,
                                               void* __restrict__ Cv,
                                               bf16* __restrict__ Vt,
                                               int M, int N, int K) {
  __shared__ bf16 sA[128 * 64];  // 16 KB
  __shared__ bf16 sB[128 * 64];  // 16 KB
  const int tid = threadIdx.x;
  const int wv = tid >> 6, lane = tid & 63;
  const int wr = wv >> 1, wc = wv & 1;
  const int lrow = lane & 15, lgrp = lane >> 4;
  const int R0 = blockIdx.y * 128, C0 = blockIdx.x * 128;

  floatx4 acc[4][4] = {};

  const int srow = lane >> 3;
  const int schk = (lane & 7) ^ srow;  // source chunk, swizzle key = row&7
  const bf16* gA = A + (size_t)(R0 + wv * 32 + srow) * K + schk * 8;
  const bf16* gB = Bt + (size_t)(C0 + wv * 32 + srow) * K + schk * 8;
  bf16* lA = sA + wv * 32 * 64;
  bf16* lB = sB + wv * 32 * 64;
  const size_t rs8 = (size_t)8 * K;

  for (int k0 = 0; k0 < K; k0 += 64) {
#pragma unroll
    for (int c = 0; c < 4; c++) {
      gl_lds16(gA + k0 + c * rs8, lA + c * 512);
      gl_lds16(gB + k0 + c * rs8, lB + c * 512);
    }
    __syncthreads();
#pragma unroll
    for (int kk = 0; kk < 2; kk++) {
      bf16x8 af[4], bfr[4];
#pragma unroll
      for (int i = 0; i < 4; i++) {
        int r = wr * 64 + i * 16 + lrow;
        af[i] = *(const bf16x8*)&sA[r * 64 + ((kk * 4 + lgrp) ^ (r & 7)) * 8];
      }
#pragma unroll
      for (int j = 0; j < 4; j++) {
        int r = wc * 64 + j * 16 + lrow;
        bfr[j] = *(const bf16x8*)&sB[r * 64 + ((kk * 4 + lgrp) ^ (r & 7)) * 8];
      }
#pragma unroll
      for (int i = 0; i < 4; i++)
#pragma unroll
        for (int j = 0; j < 4; j++)
          acc[i][j] = MFMA16(af[i], bfr[j], acc[i][j]);
    }
    __syncthreads();
  }

  const int rbase = R0 + wr * 64 + lgrp * 4;
  const int cbase = C0 + wc * 64 + lrow;
  if (OUT_BF16) {
    bf16* C = (bf16*)Cv;
#pragma unroll
    for (int i = 0; i < 4; i++)
#pragma unroll
      for (int j = 0; j < 4; j++) {
        const int col = cbase + j * 16;
        const int m192 = col % 192;
        const int hh = col / 192;
#pragma unroll
        for (int r = 0; r < 4; r++) {
          const int row = rbase + i * 16 + r;
          bf16 val = (bf16)acc[i][j][r];
          bf16* dst;
          if (FUSE_V && m192 >= 128) {
            const int sl = row & 2047;
            const int sl5 = sl & 31;
            int q5;
            if (sl5 < 16) q5 = ((sl5 >> 2) << 3) | (sl5 & 3);
            else q5 = (((((sl5 >> 2) & 3) ^ 2) << 3) | 4) | (sl5 & 3);
            const int sp = (sl & ~31) | q5;
            dst = Vt + ((size_t)(((row >> 11) * 16 + hh) * 64 + (m192 - 128))) * S_TOK + sp;
          } else {
            dst = C + (size_t)row * N + col;
          }
          *dst = val;
        }
      }
  } else {
    float* C = (float*)Cv;
#pragma unroll
    for (int i = 0; i < 4; i++)
#pragma unroll
      for (int j = 0; j < 4; j++)
#pragma unroll
        for (int r = 0; r < 4; r++)
          C[(size_t)(rbase + i * 16 + r) * N + cbase + j * 16] = acc[i][j][r];
  }
}

// ---------- GEMM 128x64 tile (out-proj: N=1024 -> 512 blocks, 2/CU) ----------
__global__ __launch_bounds__(256) void gemm_bt_n64(const bf16* __restrict__ A,
                                                   const bf16* __restrict__ Bt,
                                                   float* __restrict__ C,
                                                   int M, int N, int K) {
  __shared__ bf16 sA[128 * 64];  // 16 KB
  __shared__ bf16 sB[64 * 64];   //  8 KB
  const int tid = threadIdx.x;
  const int wv = tid >> 6, lane = tid & 63;
  const int wr = wv >> 1, wc = wv & 1;
  const int lrow = lane & 15, lgrp = lane >> 4;
  const int R0 = blockIdx.y * 128, C0 = blockIdx.x * 64;

  floatx4 acc[4][2] = {};

  const int srow = lane >> 3;
  const int schk = (lane & 7) ^ srow;
  const bf16* gA = A + (size_t)(R0 + wv * 32 + srow) * K + schk * 8;
  const bf16* gB = Bt + (size_t)(C0 + wv * 16 + srow) * K + schk * 8;
  bf16* lA = sA + wv * 32 * 64;
  bf16* lB = sB + wv * 16 * 64;
  const size_t rs8 = (size_t)8 * K;

  for (int k0 = 0; k0 < K; k0 += 64) {
#pragma unroll
    for (int c = 0; c < 4; c++) gl_lds16(gA + k0 + c * rs8, lA + c * 512);
#pragma unroll
    for (int c = 0; c < 2; c++) gl_lds16(gB + k0 + c * rs8, lB + c * 512);
    __syncthreads();
#pragma unroll
    for (int kk = 0; kk < 2; kk++) {
      bf16x8 af[4], bfr[2];
#pragma unroll
      for (int i = 0; i < 4; i++) {
        int r = wr * 64 + i * 16 + lrow;
        af[i] = *(const bf16x8*)&sA[r * 64 + ((kk * 4 + lgrp) ^ (r & 7)) * 8];
      }
#pragma unroll
      for (int j = 0; j < 2; j++) {
        int r = wc * 32 + j * 16 + lrow;
        bfr[j] = *(const bf16x8*)&sB[r * 64 + ((kk * 4 + lgrp) ^ (r & 7)) * 8];
      }
#pragma unroll
      for (int i = 0; i < 4; i++)
#pragma unroll
        for (int j = 0; j < 2; j++)
          acc[i][j] = MFMA16(af[i], bfr[j], acc[i][j]);
    }
    __syncthreads();
  }

  const int rbase = R0 + wr * 64 + lgrp * 4;
  const int cbase = C0 + wc * 32 + lrow;
#pragma unroll
  for (int i = 0; i < 4; i++)
#pragma unroll
    for (int j = 0; j < 2; j++)
#pragma unroll
      for (int r = 0; r < 4; r++)
        C[(size_t)(rbase + i * 16 + r) * N + cbase + j * 16] = acc[i][j][r];
}

// ---------- attention v12: swapped QK^T, in-register P (no sP LDS) ----------
// v11 postmortem: FETCH 70->12MB, dur 55->45.5us, Mfma 33 / VALU 29 / Occ 18
// -> all pipes <40%: the sP round-trip (32 ds_write + 8 b128 read /wave/stage
// + write->read hazard) and the ones-MFMA row-sum are the remaining overhead.
// v12: compute MFMA16(kf, qa) -> S^T (A/B frags have identical lane layouts;
// lane = one q-column, 4 keys per keytile). Each lane then owns the PV
// A-fragment directly, except key-chunks are 4-wide: keep own t0 chunk, pull
// t1 chunk from lane^32 (2 ds_bpermute per rt per group). V's key order
// within each 32-group is permuted to match (free: fused GEMM store).
// Row-sum: per-lane f32 accumulator (all of a lane's exps share one q) +
// 2 shfl_xor + shfl at the end — drops 8 ones-MFMA/wave/stage.
// Per wave/stage: LDS 40 b128+32 b32 -> 32 b128+16 bperm; MFMA 72 -> 64;
// LDS block 106 -> 64 KB.
__global__ __launch_bounds__(512, 2) void attn(const bf16* __restrict__ qkv,
                                               const bf16* __restrict__ Vt,
                                               bf16* __restrict__ vals) {
  __shared__ bf16 sK[2][128 * 64];   // 32 KB [buf][key][dh]
  __shared__ bf16 sV[2][64 * 128];   // 32 KB [buf][d][key-slot]

  const int tid = threadIdx.x;
  const int wv = tid >> 6, lane = tid & 63;
  const int lrow = lane & 15, lgrp = lane >> 4;
  const int b = blockIdx.z, h = blockIdx.x;   // x=h: same-(b,h) blocks share XCD
  const int qb = blockIdx.y * 256;

  // K staging: wave w covers key-rows [w*8,w*8+8) and [64+w*8, ...+8)
  const int srow = lane >> 3;          // 0..7
  const int scol = (lane & 7) ^ srow;  // 8-chunk swizzle, key = row&7 = srow
  const bf16* kg0 = qkv + (size_t)(b * S_TOK + wv * 8 + srow) * E3 + h * 192 + 64 + scol * 8;
  // V staging: wave w covers d-rows [w*8,w*8+8) as 2 calls of 4 rows
  const int vrow = lane >> 4;          // 0..3
  const int vchk = lane & 15;          // dest chunk (16-chunk rows)
  const int d0 = wv * 8 + vrow, d1 = d0 + 4;
  const bf16* vg0 = Vt + (size_t)((b * 16 + h) * 64 + d0) * S_TOK + (vchk ^ (d0 & 15)) * 8;
  const bf16* vg1 = Vt + (size_t)((b * 16 + h) * 64 + d1) * S_TOK + (vchk ^ (d1 & 15)) * 8;

  // Q B-fragments for two row-tiles (pre-scaled): [n=lane&15][k=lgrp*8+j]
  const bf16* qp = qkv + (size_t)(b * S_TOK + qb + wv * 32) * E3 + h * 192;
  bf16x8 qa[2][2];
#pragma unroll
  for (int rt = 0; rt < 2; rt++)
#pragma unroll
    for (int dh = 0; dh < 2; dh++)
      qa[rt][dh] = *(const bf16x8*)(qp + (size_t)(rt * 16 + lrow) * E3 + dh * 32 + lgrp * 8);

  floatx4 O[2][4] = {};
  float lsum[2] = {0.f, 0.f};
  const int xaddr = (lane ^ 32) << 2;  // ds_bpermute byte addr: pull from lane^32

  auto stage = [&](int buf, int st) {
    const bf16* kg = kg0 + (size_t)st * 128 * E3;
    gl_lds16(kg, &sK[buf][wv * 512]);
    gl_lds16(kg + (size_t)64 * E3, &sK[buf][4096 + wv * 512]);
    gl_lds16(vg0 + st * 128, &sV[buf][wv * 1024]);
    gl_lds16(vg1 + st * 128, &sV[buf][wv * 1024 + 512]);
  };

  // swapped QK^T for 32-key group g: sc[rt][t] = S^T, lane holds
  // rows key = g*32 + t*16 + lgrp*4 + r, col q = rt*16 + lrow
  auto qk_g = [&](int buf, int g, floatx4 (&sc)[2][2]) {
    bf16x8 kf[2][2];
#pragma unroll
    for (int t = 0; t < 2; t++)
#pragma unroll
      for (int dh = 0; dh < 2; dh++)
        kf[t][dh] = *(const bf16x8*)&sK[buf][(g * 32 + t * 16 + lrow) * 64 +
                                            ((dh * 4 + lgrp) ^ (lrow & 7)) * 8];
    __builtin_amdgcn_s_setprio(1);
#pragma unroll
    for (int rt = 0; rt < 2; rt++) {
      floatx4 a0 = {0.f, 0.f, 0.f, 0.f}, a1 = {0.f, 0.f, 0.f, 0.f};
      a0 = MFMA16(kf[0][0], qa[rt][0], a0);
      a0 = MFMA16(kf[0][1], qa[rt][1], a0);
      a1 = MFMA16(kf[1][0], qa[rt][0], a1);
      a1 = MFMA16(kf[1][1], qa[rt][1], a1);
      sc[rt][0] = a0;
      sc[rt][1] = a1;
    }
    __builtin_amdgcn_s_setprio(0);
  };

  // exp2 + row-sum + pack; build PV A-frag words: own t0 pair + t1 pair
  // pulled from lane^32 (matches Vt's in-group key-slot permutation)
  auto sm_g = [&](floatx4 (&sc)[2][2], unsigned (&pfw)[2][4]) {
#pragma unroll
    for (int rt = 0; rt < 2; rt++) {
      float e0 = EXP2(sc[rt][0][0]), e1 = EXP2(sc[rt][0][1]);
      float e2 = EXP2(sc[rt][0][2]), e3 = EXP2(sc[rt][0][3]);
      float e4 = EXP2(sc[rt][1][0]), e5 = EXP2(sc[rt][1][1]);
      float e6 = EXP2(sc[rt][1][2]), e7 = EXP2(sc[rt][1][3]);
      lsum[rt] += ((e0 + e1) + (e2 + e3)) + ((e4 + e5) + (e6 + e7));
      bf16x2 w;
      w[0] = (bf16)e0; w[1] = (bf16)e1;
      pfw[rt][0] = __builtin_bit_cast(unsigned, w);
      w[0] = (bf16)e2; w[1] = (bf16)e3;
      pfw[rt][1] = __builtin_bit_cast(unsigned, w);
      w[0] = (bf16)e4; w[1] = (bf16)e5;
      unsigned t10 = __builtin_bit_cast(unsigned, w);
      w[0] = (bf16)e6; w[1] = (bf16)e7;
      unsigned t11 = __builtin_bit_cast(unsigned, w);
      pfw[rt][2] = (unsigned)__builtin_amdgcn_ds_bpermute(xaddr, (int)t10);
      pfw[rt][3] = (unsigned)__builtin_amdgcn_ds_bpermute(xaddr, (int)t11);
    }
  };

  auto pv_g = [&](int buf, int g, unsigned (&pfw)[2][4]) {
    bf16x8 vf[4];
#pragma unroll
    for (int dt = 0; dt < 4; dt++)
      vf[dt] = *(const bf16x8*)&sV[buf][(dt * 16 + lrow) * 128 + ((g * 4 + lgrp) ^ lrow) * 8];
    __builtin_amdgcn_s_setprio(1);
#pragma unroll
    for (int rt = 0; rt < 2; rt++) {
      uintx4 pw = {pfw[rt][0], pfw[rt][1], pfw[rt][2], pfw[rt][3]};
      bf16x8 pf = __builtin_bit_cast(bf16x8, pw);
#pragma unroll
      for (int dt = 0; dt < 4; dt++) O[rt][dt] = MFMA16(pf, vf[dt], O[rt][dt]);
    }
    __builtin_amdgcn_s_setprio(0);
  };

  // skewed schedule: qk(g+1)/sm(g+1) cover pv(g)'s bpermute+cvt latency
  auto compute = [&](int buf) {
    floatx4 scA[2][2], scB[2][2];
    unsigned pfA[2][4], pfB[2][4];
    qk_g(buf, 0, scA); sm_g(scA, pfA);
    qk_g(buf, 1, scB); sm_g(scB, pfB); pv_g(buf, 0, pfA);
    qk_g(buf, 2, scA); sm_g(scA, pfA); pv_g(buf, 1, pfB);
    qk_g(buf, 3, scB); sm_g(scB, pfB); pv_g(buf, 2, pfA);
    pv_g(buf, 3, pfB);
  };

  stage(0, 0);
  __syncthreads();
#pragma unroll 1
  for (int st = 0; st < 16; st += 2) {
    stage(1, st + 1);
    compute(0);
    __syncthreads();
    if (st + 2 < 16) stage(0, st + 2);
    compute(1);
    __syncthreads();
  }

  // denominator: lane holds partial sum for q = lane&15 over its hi's keys;
  // reduce across hi (lane bits 4,5), then route to O's row layout via shfl
#pragma unroll
  for (int rt = 0; rt < 2; rt++) {
    lsum[rt] += __shfl_xor(lsum[rt], 16);
    lsum[rt] += __shfl_xor(lsum[rt], 32);
  }

  bf16* vout = vals + (size_t)(b * S_TOK + qb + wv * 32) * DMODEL + h * 64;
#pragma unroll
  for (int rt = 0; rt < 2; rt++)
#pragma unroll
    for (int r = 0; r < 4; r++) {
      float rs = __shfl(lsum[rt], lgrp * 4 + r);
      float rinv = __builtin_amdgcn_rcpf(rs);
#pragma unroll
      for (int dt = 0; dt < 4; dt++)
        vout[(size_t)(rt * 16 + lgrp * 4 + r) * DMODEL + dt * 16 + lrow] =
            (bf16)(O[rt][dt][r] * rinv);
    }
}

// ---------- host ----------
extern "C" void kernel_launch(void* const* d_in, const int* in_sizes, int n_in,
                              void* d_out, int out_size, void* d_ws, size_t ws_size,
                              hipStream_t stream) {
  const float* X = (const float*)d_in[0];     // (2,2048,1024)
  const float* Wqkv = (const float*)d_in[1];  // (3072,1024)
  const float* Wout = (const float*)d_in[2];  // (1024,1024)
  float* out = (float*)d_out;                 // (2,2048,1024)

  char* ws = (char*)d_ws;
  bf16* Xb = (bf16*)(ws);                          //  8 MB
  bf16* Wqb = (bf16*)(ws + ((size_t)8 << 20));     //  6 MB
  bf16* Wob = (bf16*)(ws + ((size_t)14 << 20));    //  2 MB
  bf16* qkvb = (bf16*)(ws + ((size_t)16 << 20));   // 24 MB (4096 x 3072; V-part unused)
  bf16* Vt = (bf16*)(ws + ((size_t)40 << 20));     //  8 MB (2*16*64 x 2048)
  bf16* vals = (bf16*)(ws + ((size_t)48 << 20));   //  8 MB (4096 x 1024)

  cvt_all<<<(NX + NWQ + NWO) / 2048, 256, 0, stream>>>(X, Wqkv, Wout, Xb, Wqb, Wob);

  // qkv = X @ Wqkv^T, V-part written straight to Vt (slot-permuted)
  gemm_bt<true, true><<<dim3(24, 32), 256, 0, stream>>>(Xb, Wqb, qkvb, Vt, 4096, 3072, 1024);

  // grid (h, qb, b): linear%8 = h%8 -> each XCD owns 4 (b,h) pairs' K/V (2MB, L2-fit)
  attn<<<dim3(16, 8, 2), 512, 0, stream>>>(qkvb, Vt, vals);

  // out = vals @ Wout^T : 128x64 tiles -> 512 blocks (2/CU)
  gemm_bt_n64<<<dim3(16, 32), 256, 0, stream>>>(vals, Wob, out, 4096, 1024, 1024);
}

// Round 3
// 169.964 us; speedup vs baseline: 1.0526x; 1.0096x over previous
//
#include <hip/hip_runtime.h>
#include <cstdint>
#include <cstddef>

// ---------- types ----------
typedef __bf16 bf16;
typedef __bf16 bf16x8 __attribute__((ext_vector_type(8)));
typedef __bf16 bf16x2 __attribute__((ext_vector_type(2)));
typedef float  floatx4 __attribute__((ext_vector_type(4)));
typedef unsigned uintx4 __attribute__((ext_vector_type(4)));

typedef __attribute__((address_space(1))) void gvoid_t;
typedef __attribute__((address_space(3))) void lvoid_t;

#define MFMA16(a, b, c) __builtin_amdgcn_mfma_f32_16x16x32_bf16((a), (b), (c), 0, 0, 0)

#if __has_builtin(__builtin_amdgcn_exp2f)
#define EXP2(x) __builtin_amdgcn_exp2f(x)
#else
#define EXP2(x) exp2f(x)
#endif

// B=2, S=2048, D=1024, H=16, DH=64; tokens NT=4096; E3=3072
#define S_TOK 2048
#define E3 3072
#define DMODEL 1024

// ---------- fused fp32 -> bf16 convert (X, Wqkv w/ Q-scale, Wout) ----------
#define NX 4194304
#define NWQ 3145728
#define NWO 1048576
__global__ __launch_bounds__(256) void cvt_all(const float* __restrict__ X,
                                               const float* __restrict__ Wq,
                                               const float* __restrict__ Wo,
                                               bf16* __restrict__ Xb,
                                               bf16* __restrict__ Wqb,
                                               bf16* __restrict__ Wob) {
  int i = (blockIdx.x * 256 + threadIdx.x) * 8;
  const float* s;
  bf16* d;
  float sc = 1.0f;
  int off;
  if (i < NX) {
    s = X; d = Xb; off = i;
  } else if (i < NX + NWQ) {
    off = i - NX; s = Wq; d = Wqb;
    int row = off >> 10;  // D=1024 per row; rows with e%192<64 produce Q
    if ((row % 192) < 64) sc = 0.18033688011f;  // 0.125*log2(e) pre-folded
  } else {
    off = i - NX - NWQ; s = Wo; d = Wob;
  }
  const float4* p = (const float4*)(s + off);
  float4 a = p[0], b = p[1];
  bf16x8 o;
  o[0] = (bf16)(a.x * sc); o[1] = (bf16)(a.y * sc);
  o[2] = (bf16)(a.z * sc); o[3] = (bf16)(a.w * sc);
  o[4] = (bf16)(b.x * sc); o[5] = (bf16)(b.y * sc);
  o[6] = (bf16)(b.z * sc); o[7] = (bf16)(b.w * sc);
  *(bf16x8*)(d + off) = o;
}

// ---------- async global->LDS, 16B per lane ----------
__device__ __forceinline__ void gl_lds16(const bf16* g, bf16* l) {
  __builtin_amdgcn_global_load_lds((gvoid_t*)g, (lvoid_t*)l, 16, 0, 0);
}

// ---------- GEMM: BK=64, XOR-swizzled LDS; optional fused V-transpose ----------
// FUSE_V key-slot permutation sigma (within each 32-token group), co-designed
// with attn's swapped-QK^T lane ownership: position p = lgrp*8 + t*4 + r holds
// key t*16 + lgrp*4 + r. Then lane (lrow,lgrp)'s own 8 exps (sc[rt][t][r],
// keys t*16+lgrp*4+r) ARE its PV A-fragment in slot order j=t*4+r — no
// cross-lane exchange needed at all. sigma^-1(key k) = ((k>>2)&3)*8 +
// ((k>>4)&1)*4 + (k&3). Bijective on [0,32).
template <bool OUT_BF16, bool FUSE_V>
__global__ __launch_bounds__(256) void gemm_bt(const bf16* __restrict__ A,
                                               const bf16* __restrict__ Bt,
                                               void* __restrict__ Cv,
                                               bf16* __restrict__ Vt,
                                               int M, int N, int K) {
  __shared__ bf16 sA[128 * 64];  // 16 KB
  __shared__ bf16 sB[128 * 64];  // 16 KB
  const int tid = threadIdx.x;
  const int wv = tid >> 6, lane = tid & 63;
  const int wr = wv >> 1, wc = wv & 1;
  const int lrow = lane & 15, lgrp = lane >> 4;
  const int R0 = blockIdx.y * 128, C0 = blockIdx.x * 128;

  floatx4 acc[4][4] = {};

  const int srow = lane >> 3;
  const int schk = (lane & 7) ^ srow;  // source chunk, swizzle key = row&7
  const bf16* gA = A + (size_t)(R0 + wv * 32 + srow) * K + schk * 8;
  const bf16* gB = Bt + (size_t)(C0 + wv * 32 + srow) * K + schk * 8;
  bf16* lA = sA + wv * 32 * 64;
  bf16* lB = sB + wv * 32 * 64;
  const size_t rs8 = (size_t)8 * K;

  for (int k0 = 0; k0 < K; k0 += 64) {
#pragma unroll
    for (int c = 0; c < 4; c++) {
      gl_lds16(gA + k0 + c * rs8, lA + c * 512);
      gl_lds16(gB + k0 + c * rs8, lB + c * 512);
    }
    __syncthreads();
#pragma unroll
    for (int kk = 0; kk < 2; kk++) {
      bf16x8 af[4], bfr[4];
#pragma unroll
      for (int i = 0; i < 4; i++) {
        int r = wr * 64 + i * 16 + lrow;
        af[i] = *(const bf16x8*)&sA[r * 64 + ((kk * 4 + lgrp) ^ (r & 7)) * 8];
      }
#pragma unroll
      for (int j = 0; j < 4; j++) {
        int r = wc * 64 + j * 16 + lrow;
        bfr[j] = *(const bf16x8*)&sB[r * 64 + ((kk * 4 + lgrp) ^ (r & 7)) * 8];
      }
#pragma unroll
      for (int i = 0; i < 4; i++)
#pragma unroll
        for (int j = 0; j < 4; j++)
          acc[i][j] = MFMA16(af[i], bfr[j], acc[i][j]);
    }
    __syncthreads();
  }

  const int rbase = R0 + wr * 64 + lgrp * 4;
  const int cbase = C0 + wc * 64 + lrow;
  if (OUT_BF16) {
    bf16* C = (bf16*)Cv;
#pragma unroll
    for (int i = 0; i < 4; i++)
#pragma unroll
      for (int j = 0; j < 4; j++) {
        const int col = cbase + j * 16;
        const int m192 = col % 192;
        const int hh = col / 192;
#pragma unroll
        for (int r = 0; r < 4; r++) {
          const int row = rbase + i * 16 + r;
          bf16 val = (bf16)acc[i][j][r];
          bf16* dst;
          if (FUSE_V && m192 >= 128) {
            const int sl = row & 2047;
            const int sl5 = sl & 31;
            // sigma^-1: key k -> stored position ((k>>2)&3)*8 + ((k>>4)&1)*4 + (k&3)
            const int q5 = (((sl5 >> 2) & 3) << 3) | (((sl5 >> 4) & 1) << 2) | (sl5 & 3);
            const int sp = (sl & ~31) | q5;
            dst = Vt + ((size_t)(((row >> 11) * 16 + hh) * 64 + (m192 - 128))) * S_TOK + sp;
          } else {
            dst = C + (size_t)row * N + col;
          }
          *dst = val;
        }
      }
  } else {
    float* C = (float*)Cv;
#pragma unroll
    for (int i = 0; i < 4; i++)
#pragma unroll
      for (int j = 0; j < 4; j++)
#pragma unroll
        for (int r = 0; r < 4; r++)
          C[(size_t)(rbase + i * 16 + r) * N + cbase + j * 16] = acc[i][j][r];
  }
}

// ---------- GEMM 128x64 tile (out-proj: N=1024 -> 512 blocks, 2/CU) ----------
__global__ __launch_bounds__(256) void gemm_bt_n64(const bf16* __restrict__ A,
                                                   const bf16* __restrict__ Bt,
                                                   float* __restrict__ C,
                                                   int M, int N, int K) {
  __shared__ bf16 sA[128 * 64];  // 16 KB
  __shared__ bf16 sB[64 * 64];   //  8 KB
  const int tid = threadIdx.x;
  const int wv = tid >> 6, lane = tid & 63;
  const int wr = wv >> 1, wc = wv & 1;
  const int lrow = lane & 15, lgrp = lane >> 4;
  const int R0 = blockIdx.y * 128, C0 = blockIdx.x * 64;

  floatx4 acc[4][2] = {};

  const int srow = lane >> 3;
  const int schk = (lane & 7) ^ srow;
  const bf16* gA = A + (size_t)(R0 + wv * 32 + srow) * K + schk * 8;
  const bf16* gB = Bt + (size_t)(C0 + wv * 16 + srow) * K + schk * 8;
  bf16* lA = sA + wv * 32 * 64;
  bf16* lB = sB + wv * 16 * 64;
  const size_t rs8 = (size_t)8 * K;

  for (int k0 = 0; k0 < K; k0 += 64) {
#pragma unroll
    for (int c = 0; c < 4; c++) gl_lds16(gA + k0 + c * rs8, lA + c * 512);
#pragma unroll
    for (int c = 0; c < 2; c++) gl_lds16(gB + k0 + c * rs8, lB + c * 512);
    __syncthreads();
#pragma unroll
    for (int kk = 0; kk < 2; kk++) {
      bf16x8 af[4], bfr[2];
#pragma unroll
      for (int i = 0; i < 4; i++) {
        int r = wr * 64 + i * 16 + lrow;
        af[i] = *(const bf16x8*)&sA[r * 64 + ((kk * 4 + lgrp) ^ (r & 7)) * 8];
      }
#pragma unroll
      for (int j = 0; j < 2; j++) {
        int r = wc * 32 + j * 16 + lrow;
        bfr[j] = *(const bf16x8*)&sB[r * 64 + ((kk * 4 + lgrp) ^ (r & 7)) * 8];
      }
#pragma unroll
      for (int i = 0; i < 4; i++)
#pragma unroll
        for (int j = 0; j < 2; j++)
          acc[i][j] = MFMA16(af[i], bfr[j], acc[i][j]);
    }
    __syncthreads();
  }

  const int rbase = R0 + wr * 64 + lgrp * 4;
  const int cbase = C0 + wc * 32 + lrow;
#pragma unroll
  for (int i = 0; i < 4; i++)
#pragma unroll
    for (int j = 0; j < 2; j++)
#pragma unroll
      for (int r = 0; r < 4; r++)
        C[(size_t)(rbase + i * 16 + r) * N + cbase + j * 16] = acc[i][j][r];
}

// ---------- attention v13: zero-exchange P (corrected sigma) ----------
// v12 postmortem: sP removal was latency-hidden (flat time, conflicts -> 0);
// per-stage floor is ~2400cyc (MFMA 2480/SIMD vs LDS-read 2340/CU), measured
// 6700 -> dependency-chain slack. v12's 16 ds_bpermute/wave/stage (inside the
// sm->pv chain: ~740 LDS-port cyc/stage/CU + lgkmcnt latency) were a design
// error: with swapped QK^T the lane computing sc[rt][0] AND sc[rt][1] already
// owns all 8 keys of its PV A-fragment slots lgrp*8+j under sigma
// (position p=lgrp*8+t*4+r holds key t*16+lgrp*4+r). v13: pack own exps
// directly, zero cross-lane ops in the main loop.
__global__ __launch_bounds__(512, 2) void attn(const bf16* __restrict__ qkv,
                                               const bf16* __restrict__ Vt,
                                               bf16* __restrict__ vals) {
  __shared__ bf16 sK[2][128 * 64];   // 32 KB [buf][key][dh]
  __shared__ bf16 sV[2][64 * 128];   // 32 KB [buf][d][key-slot]

  const int tid = threadIdx.x;
  const int wv = tid >> 6, lane = tid & 63;
  const int lrow = lane & 15, lgrp = lane >> 4;
  const int b = blockIdx.z, h = blockIdx.x;   // x=h: same-(b,h) blocks share XCD
  const int qb = blockIdx.y * 256;

  // K staging: wave w covers key-rows [w*8,w*8+8) and [64+w*8, ...+8)
  const int srow = lane >> 3;          // 0..7
  const int scol = (lane & 7) ^ srow;  // 8-chunk swizzle, key = row&7 = srow
  const bf16* kg0 = qkv + (size_t)(b * S_TOK + wv * 8 + srow) * E3 + h * 192 + 64 + scol * 8;
  // V staging: wave w covers d-rows [w*8,w*8+8) as 2 calls of 4 rows
  const int vrow = lane >> 4;          // 0..3
  const int vchk = lane & 15;          // dest chunk (16-chunk rows)
  const int d0 = wv * 8 + vrow, d1 = d0 + 4;
  const bf16* vg0 = Vt + (size_t)((b * 16 + h) * 64 + d0) * S_TOK + (vchk ^ (d0 & 15)) * 8;
  const bf16* vg1 = Vt + (size_t)((b * 16 + h) * 64 + d1) * S_TOK + (vchk ^ (d1 & 15)) * 8;

  // Q B-fragments for two row-tiles (pre-scaled): [n=lane&15][k=lgrp*8+j]
  const bf16* qp = qkv + (size_t)(b * S_TOK + qb + wv * 32) * E3 + h * 192;
  bf16x8 qa[2][2];
#pragma unroll
  for (int rt = 0; rt < 2; rt++)
#pragma unroll
    for (int dh = 0; dh < 2; dh++)
      qa[rt][dh] = *(const bf16x8*)(qp + (size_t)(rt * 16 + lrow) * E3 + dh * 32 + lgrp * 8);

  floatx4 O[2][4] = {};
  float lsum[2] = {0.f, 0.f};

  auto stage = [&](int buf, int st) {
    const bf16* kg = kg0 + (size_t)st * 128 * E3;
    gl_lds16(kg, &sK[buf][wv * 512]);
    gl_lds16(kg + (size_t)64 * E3, &sK[buf][4096 + wv * 512]);
    gl_lds16(vg0 + st * 128, &sV[buf][wv * 1024]);
    gl_lds16(vg1 + st * 128, &sV[buf][wv * 1024 + 512]);
  };

  // swapped QK^T for 32-key group g: sc[rt][t] = S^T, lane holds
  // rows key = g*32 + t*16 + lgrp*4 + r, col q = rt*16 + lrow
  auto qk_g = [&](int buf, int g, floatx4 (&sc)[2][2]) {
    bf16x8 kf[2][2];
#pragma unroll
    for (int t = 0; t < 2; t++)
#pragma unroll
      for (int dh = 0; dh < 2; dh++)
        kf[t][dh] = *(const bf16x8*)&sK[buf][(g * 32 + t * 16 + lrow) * 64 +
                                            ((dh * 4 + lgrp) ^ (lrow & 7)) * 8];
    __builtin_amdgcn_s_setprio(1);
#pragma unroll
    for (int rt = 0; rt < 2; rt++) {
      floatx4 a0 = {0.f, 0.f, 0.f, 0.f}, a1 = {0.f, 0.f, 0.f, 0.f};
      a0 = MFMA16(kf[0][0], qa[rt][0], a0);
      a0 = MFMA16(kf[0][1], qa[rt][1], a0);
      a1 = MFMA16(kf[1][0], qa[rt][0], a1);
      a1 = MFMA16(kf[1][1], qa[rt][1], a1);
      sc[rt][0] = a0;
      sc[rt][1] = a1;
    }
    __builtin_amdgcn_s_setprio(0);
  };

  // exp2 + row-sum + pack own 8 exps -> PV A-frag (slot j = t*4+r, sigma'd V)
  auto sm_g = [&](floatx4 (&sc)[2][2], unsigned (&pfw)[2][4]) {
#pragma unroll
    for (int rt = 0; rt < 2; rt++) {
      float e0 = EXP2(sc[rt][0][0]), e1 = EXP2(sc[rt][0][1]);
      float e2 = EXP2(sc[rt][0][2]), e3 = EXP2(sc[rt][0][3]);
      float e4 = EXP2(sc[rt][1][0]), e5 = EXP2(sc[rt][1][1]);
      float e6 = EXP2(sc[rt][1][2]), e7 = EXP2(sc[rt][1][3]);
      lsum[rt] += ((e0 + e1) + (e2 + e3)) + ((e4 + e5) + (e6 + e7));
      bf16x2 w;
      w[0] = (bf16)e0; w[1] = (bf16)e1;
      pfw[rt][0] = __builtin_bit_cast(unsigned, w);
      w[0] = (bf16)e2; w[1] = (bf16)e3;
      pfw[rt][1] = __builtin_bit_cast(unsigned, w);
      w[0] = (bf16)e4; w[1] = (bf16)e5;
      pfw[rt][2] = __builtin_bit_cast(unsigned, w);
      w[0] = (bf16)e6; w[1] = (bf16)e7;
      pfw[rt][3] = __builtin_bit_cast(unsigned, w);
    }
  };

  auto pv_g = [&](int buf, int g, unsigned (&pfw)[2][4]) {
    bf16x8 vf[4];
#pragma unroll
    for (int dt = 0; dt < 4; dt++)
      vf[dt] = *(const bf16x8*)&sV[buf][(dt * 16 + lrow) * 128 + ((g * 4 + lgrp) ^ lrow) * 8];
    __builtin_amdgcn_s_setprio(1);
#pragma unroll
    for (int rt = 0; rt < 2; rt++) {
      uintx4 pw = {pfw[rt][0], pfw[rt][1], pfw[rt][2], pfw[rt][3]};
      bf16x8 pf = __builtin_bit_cast(bf16x8, pw);
#pragma unroll
      for (int dt = 0; dt < 4; dt++) O[rt][dt] = MFMA16(pf, vf[dt], O[rt][dt]);
    }
    __builtin_amdgcn_s_setprio(0);
  };

  // skewed schedule: qk(g+1)/sm(g+1) cover pv(g)'s vf-read + cvt latency
  auto compute = [&](int buf) {
    floatx4 scA[2][2], scB[2][2];
    unsigned pfA[2][4], pfB[2][4];
    qk_g(buf, 0, scA); sm_g(scA, pfA);
    qk_g(buf, 1, scB); sm_g(scB, pfB); pv_g(buf, 0, pfA);
    qk_g(buf, 2, scA); sm_g(scA, pfA); pv_g(buf, 1, pfB);
    qk_g(buf, 3, scB); sm_g(scB, pfB); pv_g(buf, 2, pfA);
    pv_g(buf, 3, pfB);
  };

  stage(0, 0);
  __syncthreads();
#pragma unroll 1
  for (int st = 0; st < 16; st += 2) {
    stage(1, st + 1);
    compute(0);
    __syncthreads();
    if (st + 2 < 16) stage(0, st + 2);
    compute(1);
    __syncthreads();
  }

  // denominator: lane holds partial sum for q = lane&15 over its lgrp's keys;
  // reduce across lgrp (lane bits 4,5), then route to O's row layout via shfl
#pragma unroll
  for (int rt = 0; rt < 2; rt++) {
    lsum[rt] += __shfl_xor(lsum[rt], 16);
    lsum[rt] += __shfl_xor(lsum[rt], 32);
  }

  bf16* vout = vals + (size_t)(b * S_TOK + qb + wv * 32) * DMODEL + h * 64;
#pragma unroll
  for (int rt = 0; rt < 2; rt++)
#pragma unroll
    for (int r = 0; r < 4; r++) {
      float rs = __shfl(lsum[rt], lgrp * 4 + r);
      float rinv = __builtin_amdgcn_rcpf(rs);
#pragma unroll
      for (int dt = 0; dt < 4; dt++)
        vout[(size_t)(rt * 16 + lgrp * 4 + r) * DMODEL + dt * 16 + lrow] =
            (bf16)(O[rt][dt][r] * rinv);
    }
}

// ---------- host ----------
extern "C" void kernel_launch(void* const* d_in, const int* in_sizes, int n_in,
                              void* d_out, int out_size, void* d_ws, size_t ws_size,
                              hipStream_t stream) {
  const float* X = (const float*)d_in[0];     // (2,2048,1024)
  const float* Wqkv = (const float*)d_in[1];  // (3072,1024)
  const float* Wout = (const float*)d_in[2];  // (1024,1024)
  float* out = (float*)d_out;                 // (2,2048,1024)

  char* ws = (char*)d_ws;
  bf16* Xb = (bf16*)(ws);                          //  8 MB
  bf16* Wqb = (bf16*)(ws + ((size_t)8 << 20));     //  6 MB
  bf16* Wob = (bf16*)(ws + ((size_t)14 << 20));    //  2 MB
  bf16* qkvb = (bf16*)(ws + ((size_t)16 << 20));   // 24 MB (4096 x 3072; V-part unused)
  bf16* Vt = (bf16*)(ws + ((size_t)40 << 20));     //  8 MB (2*16*64 x 2048)
  bf16* vals = (bf16*)(ws + ((size_t)48 << 20));   //  8 MB (4096 x 1024)

  cvt_all<<<(NX + NWQ + NWO) / 2048, 256, 0, stream>>>(X, Wqkv, Wout, Xb, Wqb, Wob);

  // qkv = X @ Wqkv^T, V-part written straight to Vt (sigma-permuted)
  gemm_bt<true, true><<<dim3(24, 32), 256, 0, stream>>>(Xb, Wqb, qkvb, Vt, 4096, 3072, 1024);

  // grid (h, qb, b): linear%8 = h%8 -> each XCD owns 4 (b,h) pairs' K/V (2MB, L2-fit)
  attn<<<dim3(16, 8, 2), 512, 0, stream>>>(qkvb, Vt, vals);

  // out = vals @ Wout^T : 128x64 tiles -> 512 blocks (2/CU)
  gemm_bt_n64<<<dim3(16, 32), 256, 0, stream>>>(vals, Wob, out, 4096, 1024, 1024);
}